// Round 8
// baseline (712.187 us; speedup 1.0000x reference)
//
#include <hip/hip_runtime.h>

typedef unsigned short u16;
typedef short short8 __attribute__((ext_vector_type(8)));
typedef unsigned short ushort8 __attribute__((ext_vector_type(8)));
typedef unsigned short bf16x4 __attribute__((ext_vector_type(4)));
typedef float f32x4 __attribute__((ext_vector_type(4)));

#define DEVINL __device__ __forceinline__

DEVINL float bf2f(u16 u) {
  unsigned int x = ((unsigned int)u) << 16;
  return __builtin_bit_cast(float, x);
}
DEVINL u16 f2bf(float f) {
  unsigned int x = __builtin_bit_cast(unsigned int, f);
  x += 0x7FFFu + ((x >> 16) & 1u);  // RNE
  return (u16)(x >> 16);
}

// Problem constants: B=2, S=2048, E=1024, H=16, DH=64
// Inputs float32; big operands converted once to bf16; MFMA internally;
// final output written as float32.

// ---------------------------------------------------------------------------
// Fused f32 -> bf16 conversion of query + 4 weight matrices.
// ---------------------------------------------------------------------------
__global__ __launch_bounds__(256) void cvt_all(
    const float* __restrict__ q, const float* __restrict__ wq,
    const float* __restrict__ wk, const float* __restrict__ wv,
    const float* __restrict__ wo, u16* __restrict__ out) {
  int i = blockIdx.x * 256 + threadIdx.x;  // < 1048576
  const float* src;
  size_t off8;
  if (i < 524288) { src = q;  off8 = i; }
  else if (i < 655360) { src = wq; off8 = i - 524288; }
  else if (i < 786432) { src = wk; off8 = i - 655360; }
  else if (i < 917504) { src = wv; off8 = i - 786432; }
  else { src = wo; off8 = i - 917504; }
  f32x4 a = ((const f32x4*)src)[2 * off8];
  f32x4 b = ((const f32x4*)src)[2 * off8 + 1];
  ushort8 o;
#pragma unroll
  for (int e = 0; e < 4; ++e) o[e] = f2bf(a[e]);
#pragma unroll
  for (int e = 0; e < 4; ++e) o[4 + e] = f2bf(b[e]);
  ((ushort8*)out)[i] = o;
}

// ---------------------------------------------------------------------------
// NT GEMM (bf16 in via MFMA): C[i,j] = scale * sum_k A[i,k]*B[j,k] (+ bias[j])
// ---------------------------------------------------------------------------
template <int BM, int BN, bool TRANSV, bool HASBIAS, bool OUTF32>
__global__ __launch_bounds__(256) void gemm_nt(
    const u16* __restrict__ A, const u16* __restrict__ Bm,
    const float* __restrict__ bias, void* __restrict__ C,
    int K, int lda, int ldb, int ldc, float scale,
    long long sAh, long long sBh, long long sCh) {
  constexpr int LDSS = 40;  // padded LDS row stride (u16)
  constexpr int WM = BM / 2, WN = BN / 2, FM = WM / 16, FN = WN / 16;
  constexpr int AIN = BM / 64;
  constexpr int BIN = BN / 64;

  __shared__ alignas(16) u16 As[BM * LDSS];
  __shared__ alignas(16) u16 Bs[BN * LDSS];

  const int tid = threadIdx.x;
  const int lane = tid & 63;
  const int wv = tid >> 6;
  const int wy = wv >> 1, wx = wv & 1;
  const int quad = lane >> 4, mrow = lane & 15;

  const int z = blockIdx.z;
  const u16* Ap = A + z * sAh;
  const u16* Bp = Bm + z * sBh;
  u16* Cp = (u16*)C + z * sCh;
  float* Cf = (float*)C + z * sCh;

  const int row0 = blockIdx.y * BM;
  const int col0 = blockIdx.x * BN;

  f32x4 acc[FM][FN];
#pragma unroll
  for (int i = 0; i < FM; ++i)
#pragma unroll
    for (int j = 0; j < FN; ++j) acc[i][j] = f32x4{0.f, 0.f, 0.f, 0.f};

  for (int k0 = 0; k0 < K; k0 += 32) {
    ushort8 ta[AIN], tb[BIN];
#pragma unroll
    for (int r = 0; r < AIN; ++r) {
      int idx = r * 256 + tid;
      int row = idx >> 2, ch = idx & 3;
      ta[r] = *(const ushort8*)(Ap + (size_t)(row0 + row) * lda + k0 + ch * 8);
    }
#pragma unroll
    for (int r = 0; r < BIN; ++r) {
      int idx = r * 256 + tid;
      int row = idx >> 2, ch = idx & 3;
      tb[r] = *(const ushort8*)(Bp + (size_t)(col0 + row) * ldb + k0 + ch * 8);
    }
    __syncthreads();  // previous iteration's LDS reads done
#pragma unroll
    for (int r = 0; r < AIN; ++r) {
      int idx = r * 256 + tid;
      int row = idx >> 2, ch = idx & 3;
      *(ushort8*)&As[row * LDSS + ch * 8] = ta[r];
    }
#pragma unroll
    for (int r = 0; r < BIN; ++r) {
      int idx = r * 256 + tid;
      int row = idx >> 2, ch = idx & 3;
      *(ushort8*)&Bs[row * LDSS + ch * 8] = tb[r];
    }
    __syncthreads();

    short8 af[FM], bfr[FN];
#pragma unroll
    for (int mi = 0; mi < FM; ++mi)
      af[mi] = *(const short8*)&As[(wy * WM + mi * 16 + mrow) * LDSS + quad * 8];
#pragma unroll
    for (int ni = 0; ni < FN; ++ni)
      bfr[ni] = *(const short8*)&Bs[(wx * WN + ni * 16 + mrow) * LDSS + quad * 8];
#pragma unroll
    for (int mi = 0; mi < FM; ++mi)
#pragma unroll
      for (int ni = 0; ni < FN; ++ni)
        acc[mi][ni] = __builtin_amdgcn_mfma_f32_16x16x32_bf16(
            af[mi], bfr[ni], acc[mi][ni], 0, 0, 0);
  }

  // Epilogue. C/D layout: col = lane&15, row = quad*4 + r  [m89/m91 verified]
#pragma unroll
  for (int mi = 0; mi < FM; ++mi) {
    const int rowb = row0 + wy * WM + mi * 16 + quad * 4;
#pragma unroll
    for (int ni = 0; ni < FN; ++ni) {
      const int col = col0 + wx * WN + ni * 16 + mrow;
      float bv = 0.f;
      if (HASBIAS) bv = bias[col];
      f32x4 v = acc[mi][ni];
      if (OUTF32) {
#pragma unroll
        for (int r = 0; r < 4; ++r)
          Cf[(size_t)(rowb + r) * ldc + col] = v[r] * scale + bv;
      } else if (!TRANSV) {
#pragma unroll
        for (int r = 0; r < 4; ++r)
          Cp[(size_t)(rowb + r) * ldc + col] = f2bf(v[r] * scale + bv);
      } else {
        // Ct[b][col][s], per-batch stride E*S = 2097152
        const int bb = rowb >> 11;
        const int ss = rowb & 2047;
        bf16x4 pk;
#pragma unroll
        for (int r = 0; r < 4; ++r) pk[r] = f2bf(v[r] * scale + bv);
        *(bf16x4*)(Cp + (size_t)bb * 2097152 + (size_t)col * 2048 + ss) = pk;
      }
    }
  }
}

// ---------------------------------------------------------------------------
// Fused conv(KS=3, cross-head) + online softmax + PV, flash-style, v2.
// 1024 threads = 16 waves = 2 independent k-groups of 8 waves; group g owns
// k in [g*1024, g*1024+1024) in 32 chunks of 32. q-tile = 8, grid 256/batch.
// Per group per chunk: stage S-chunk transposed (T[q][kk][h], TROW=24,
// conflict-spread b16 scatter), conv via verified MFMA mapping (m=h, n=k,
// kdim=(i,d)), online softmax in registers, P -> Pl (A-layout), PV MFMA with
// V B-frags direct from global (L2-resident). SC loads for chunk c+1 are
// issued at the top of iteration c (in flight across both barriers).
// End: flash split-k merge of (m,l,O) across groups via LDS (arena reuse).
// conv_b skipped: constant along softmax (k) axis -> cancels exactly.
// ---------------------------------------------------------------------------
__global__ __launch_bounds__(1024, 4) void conv_attn(
    const u16* __restrict__ SC, const u16* __restrict__ Vt,
    const float* __restrict__ cw, u16* __restrict__ At) {
  constexpr int TROW = 24;             // u16 stride per kk row (48B)
  constexpr int TSLAB = 34 * TROW;     // per-q slab: kk 0..33
  constexpr int TGRP = 8 * TSLAB;      // per-group T (6528 u16)
  constexpr int PROW = 40;             // Pl k stride (32 + 8 pad, 80B)
  constexpr int PGRP = 16 * 8 * PROW;  // 5120 u16
  __shared__ alignas(16) u16 arena[2 * TGRP + 2 * PGRP];  // 46.6 KB (merge reuses)
  __shared__ float alphaS[2][16][8];
  __shared__ float lmM[2][8][16];
  __shared__ float lmL[2][8][16];

  const int tid = threadIdx.x;
  const int lane = tid & 63;
  const int wv = tid >> 6;   // 0..15
  const int g = wv >> 3;     // k-group
  const int wl = wv & 7;     // wave within group
  const int tidg = tid & 511;
  const int n = lane & 15;
  const int quad = lane >> 4;
  const int q0 = blockIdx.x * 8;
  const int kbase = g * 1024;

  u16* Tg = arena + g * TGRP;
  u16* Plg = arena + 2 * TGRP + g * PGRP;

  // conv A-frags (round-6/7 verified): lane's M-row h = n; kdim=quad*8+j->(i,d)
  short8 a1, a2;
#pragma unroll
  for (int j = 0; j < 8; ++j) {
    const int kd = quad * 8 + j;
    const int i = kd & 15, d = kd >> 4;
    a1[j] = (short)f2bf(cw[n * 48 + i * 3 + d]);
    a2[j] = (quad < 2) ? (short)f2bf(cw[n * 48 + kd * 3 + 2]) : (short)0;
  }

  float m[4], l[4];
#pragma unroll
  for (int r = 0; r < 4; ++r) { m[r] = -3e38f; l[r] = 0.f; }
  f32x4 O[2][4];
#pragma unroll
  for (int hh = 0; hh < 2; ++hh)
#pragma unroll
    for (int dt = 0; dt < 4; ++dt) O[hh][dt] = f32x4{0.f, 0.f, 0.f, 0.f};

  // staging decode (fixed per thread): 512 thr/group cover 128 (q,h) rows x 4 k8
  const int k8 = tidg & 3;
  const int pair = tidg >> 2;  // 0..127
  const int sq = pair >> 4, sh = pair & 15;
  const size_t srow = ((size_t)(sh * 2048 + q0 + sq)) * 2048;
  const int hside = tidg >> 7;  // halo (tidg<256)
  const int hp = tidg & 127;
  const int hq = hp >> 4, hh2 = hp & 15;
  const size_t hrow = ((size_t)(hh2 * 2048 + q0 + hq)) * 2048;

  // preload chunk 0
  ushort8 tv = *(const ushort8*)(SC + srow + kbase + k8 * 8);
  u16 th = 0;
  if (tidg < 256) {
    const int k = kbase + (hside ? 32 : -1);
    th = ((unsigned)k < 2048u) ? SC[hrow + k] : (u16)0;
  }

#pragma unroll 1
  for (int c = 0; c < 32; ++c) {
    const int k0 = kbase + c * 32;
    // ---- write T from prefetched regs ----
#pragma unroll
    for (int e0 = 0; e0 < 8; ++e0) {
      const int e = (e0 + pair) & 7;  // rotate to spread banks
      Tg[sq * TSLAB + (1 + k8 * 8 + e) * TROW + sh] = tv[e];
    }
    if (tidg < 256) Tg[hq * TSLAB + (hside ? 33 : 0) * TROW + hh2] = th;

    // ---- prefetch next chunk (in flight across both barriers) ----
    if (c < 31) {
      tv = *(const ushort8*)(SC + srow + (k0 + 32) + k8 * 8);
      if (tidg < 256) {
        const int k = (k0 + 32) + (hside ? 32 : -1);
        th = ((unsigned)k < 2048u) ? SC[hrow + k] : (u16)0;
      }
    }

    // ---- PV of previous chunk ----
    if (c > 0) {
      const int k0p = k0 - 32;
#pragma unroll
      for (int hh = 0; hh < 2; ++hh) {
        const int h = wl * 2 + hh;
        float av[4];
#pragma unroll
        for (int r = 0; r < 4; ++r) av[r] = alphaS[g][h][(quad * 4 + r) & 7];
#pragma unroll
        for (int dt = 0; dt < 4; ++dt)
#pragma unroll
          for (int r = 0; r < 4; ++r) O[hh][dt][r] *= av[r];
        const short8 aF = *(const short8*)&Plg[(h * 8 + (n & 7)) * PROW + quad * 8];
#pragma unroll
        for (int dt = 0; dt < 4; ++dt) {
          const short8 bF = *(const short8*)(Vt + (size_t)(h * 64 + dt * 16 + n) * 2048 + k0p + quad * 8);
          O[hh][dt] = __builtin_amdgcn_mfma_f32_16x16x32_bf16(aF, bF, O[hh][dt], 0, 0, 0);
        }
      }
    }
    __syncthreads();  // T ready; Pl/alphaS consumed

    // ---- conv + online softmax for q = wl ----
    {
      f32x4 x[2];
#pragma unroll
      for (int kt = 0; kt < 2; ++kt) {
        const short8 b1 = *(const short8*)&Tg[wl * TSLAB + (kt * 16 + n + (quad >> 1)) * TROW + (quad & 1) * 8];
        const short8 b2 = *(const short8*)&Tg[wl * TSLAB + (kt * 16 + n + 2) * TROW + (quad & 1) * 8];
        f32x4 acc = f32x4{0.f, 0.f, 0.f, 0.f};
        acc = __builtin_amdgcn_mfma_f32_16x16x32_bf16(a1, b1, acc, 0, 0, 0);
        acc = __builtin_amdgcn_mfma_f32_16x16x32_bf16(a2, b2, acc, 0, 0, 0);
        x[kt] = acc;
      }
      float mn[4], al[4], s[4];
#pragma unroll
      for (int r = 0; r < 4; ++r) {
        float cm = fmaxf(x[0][r], x[1][r]);
#pragma unroll
        for (int off = 1; off < 16; off <<= 1) cm = fmaxf(cm, __shfl_xor(cm, off));
        mn[r] = fmaxf(m[r], cm);
        al[r] = __expf(m[r] - mn[r]);
        s[r] = 0.f;
      }
#pragma unroll
      for (int kt = 0; kt < 2; ++kt)
#pragma unroll
        for (int r = 0; r < 4; ++r) {
          x[kt][r] = __expf(x[kt][r] - mn[r]);
          s[r] += x[kt][r];
        }
#pragma unroll
      for (int r = 0; r < 4; ++r) {
#pragma unroll
        for (int off = 1; off < 16; off <<= 1) s[r] += __shfl_xor(s[r], off);
        l[r] = l[r] * al[r] + s[r];
        m[r] = mn[r];
      }
#pragma unroll
      for (int kt = 0; kt < 2; ++kt)
#pragma unroll
        for (int r = 0; r < 4; ++r)
          Plg[((quad * 4 + r) * 8 + wl) * PROW + kt * 16 + n] = f2bf(x[kt][r]);
      if (n == 0)
#pragma unroll
        for (int r = 0; r < 4; ++r) alphaS[g][quad * 4 + r][wl] = al[r];
    }
    __syncthreads();  // Pl/alphaS ready for PV next iter
  }

  // ---- final PV (local chunk 31) ----
  {
    const int k0p = kbase + 31 * 32;
#pragma unroll
    for (int hh = 0; hh < 2; ++hh) {
      const int h = wl * 2 + hh;
      float av[4];
#pragma unroll
      for (int r = 0; r < 4; ++r) av[r] = alphaS[g][h][(quad * 4 + r) & 7];
#pragma unroll
      for (int dt = 0; dt < 4; ++dt)
#pragma unroll
        for (int r = 0; r < 4; ++r) O[hh][dt][r] *= av[r];
      const short8 aF = *(const short8*)&Plg[(h * 8 + (n & 7)) * PROW + quad * 8];
#pragma unroll
      for (int dt = 0; dt < 4; ++dt) {
        const short8 bF = *(const short8*)(Vt + (size_t)(h * 64 + dt * 16 + n) * 2048 + k0p + quad * 8);
        O[hh][dt] = __builtin_amdgcn_mfma_f32_16x16x32_bf16(aF, bF, O[hh][dt], 0, 0, 0);
      }
    }
  }
  // publish per-(q,h) online-softmax state
  if (n == 0)
#pragma unroll
    for (int r = 0; r < 4; ++r) {
      lmM[g][wl][quad * 4 + r] = m[r];
      lmL[g][wl][quad * 4 + r] = l[r];
    }
  __syncthreads();

  // ---- cross-group merge (flash split-k combine); arena reused for O ----
  float* Oex = (float*)arena;  // [q 8][h 16][d 64] f32 = 32 KB
  if (g == 1 && quad < 2) {
#pragma unroll
    for (int hh = 0; hh < 2; ++hh) {
      const int h = wl * 2 + hh;
#pragma unroll
      for (int r = 0; r < 4; ++r) {
        const int qq = quad * 4 + r;
        const float M = fmaxf(lmM[0][qq][h], lmM[1][qq][h]);
        const float sc1 = __expf(lmM[1][qq][h] - M);
#pragma unroll
        for (int dt = 0; dt < 4; ++dt)
          Oex[(qq * 16 + h) * 64 + dt * 16 + n] = O[hh][dt][r] * sc1;
      }
    }
  }
  __syncthreads();
  if (g == 0 && quad < 2) {
#pragma unroll
    for (int hh = 0; hh < 2; ++hh) {
      const int h = wl * 2 + hh;
#pragma unroll
      for (int r = 0; r < 4; ++r) {
        const int qq = quad * 4 + r;
        const float m0v = lmM[0][qq][h], m1v = lmM[1][qq][h];
        const float M = fmaxf(m0v, m1v);
        const float sc0 = __expf(m0v - M), sc1 = __expf(m1v - M);
        const float inv = 1.f / (sc0 * lmL[0][qq][h] + sc1 * lmL[1][qq][h]);
#pragma unroll
        for (int dt = 0; dt < 4; ++dt) {
          const float v =
              (O[hh][dt][r] * sc0 + Oex[(qq * 16 + h) * 64 + dt * 16 + n]) * inv;
          At[(size_t)(q0 + qq) * 1024 + h * 64 + dt * 16 + n] = f2bf(v);
        }
      }
    }
  }
}

// Diagnostic: fill f32 output with 2000.0 (ws-too-small marker).
__global__ void fill_diag(float* out, int n) {
  int i = blockIdx.x * 256 + threadIdx.x;
  if (i < n) out[i] = 2000.0f;
}

extern "C" void kernel_launch(void* const* d_in, const int* in_sizes, int n_in,
                              void* d_out, int out_size, void* d_ws, size_t ws_size,
                              hipStream_t stream) {
  const float* query = (const float*)d_in[0];
  const float* Wq = (const float*)d_in[1];
  const float* bq = (const float*)d_in[2];
  const float* Wk = (const float*)d_in[3];
  const float* bk = (const float*)d_in[4];
  const float* Wv = (const float*)d_in[5];
  const float* bv = (const float*)d_in[6];
  const float* Wo = (const float*)d_in[7];
  const float* bo = (const float*)d_in[8];
  const float* cw = (const float*)d_in[9];
  // d_in[10] (conv_b) intentionally unused: cancels in softmax.

  const size_t SE = (size_t)4096 * 1024;  // B*S*E elems
  const size_t WE = (size_t)1024 * 1024;  // E*E elems
  const size_t SCE = (size_t)16 * 2048 * 2048;  // per-batch scores elems
  const size_t fixedB = ((SE + 4 * WE) + 4 * SE) * sizeof(u16);  // 48 MiB
  if (ws_size < fixedB + SCE * sizeof(u16)) {  // 48 + 128 MiB
    fill_diag<<<dim3((out_size + 255) / 256), dim3(256), 0, stream>>>(
        (float*)d_out, out_size);
    return;
  }

  u16* ws = (u16*)d_ws;
  u16* Qb = ws;              // bf16 query [b][s][e]
  u16* Wqb = Qb + SE;        // bf16 weights (contiguous after Qb for cvt_all)
  u16* Wkb = Wqb + WE;
  u16* Wvb = Wkb + WE;
  u16* Wob = Wvb + WE;
  u16* Qw = Wob + WE;        // [b][s][e]
  u16* Kw = Qw + SE;         // [b][s][e]
  u16* Vt = Kw + SE;         // [b][e][s] transposed V
  u16* At = Vt + SE;         // attention output [b][s][e] (bf16)
  u16* SC = At + SE;         // raw scores, one batch at a time [h][q][k]

  dim3 blk(256);
  cvt_all<<<dim3(4096), blk, 0, stream>>>(query, Wq, Wk, Wv, Wo, Qb);

  // Q/K/V projections (M=4096, N=1024, K=1024), bf16 out
  gemm_nt<128, 128, false, true, false><<<dim3(8, 32, 1), blk, 0, stream>>>(
      Qb, Wqb, bq, Qw, 1024, 1024, 1024, 1024, 1.f, 0, 0, 0);
  gemm_nt<128, 128, false, true, false><<<dim3(8, 32, 1), blk, 0, stream>>>(
      Qb, Wkb, bk, Kw, 1024, 1024, 1024, 1024, 1.f, 0, 0, 0);
  gemm_nt<128, 128, true, true, false><<<dim3(8, 32, 1), blk, 0, stream>>>(
      Qb, Wvb, bv, Vt, 1024, 1024, 1024, 1024, 1.f, 0, 0, 0);

  for (int b = 0; b < 2; ++b) {
    const size_t bQK = (size_t)b * 2097152;
    // raw scores = Q Kh^T / 8 per head: M=N=2048, K=64, z = head
    gemm_nt<128, 128, false, false, false>
        <<<dim3(16, 16, 16), blk, 0, stream>>>(
            Qw + bQK, Kw + bQK, nullptr, SC,
            64, 1024, 1024, 2048, 0.125f, 64LL, 64LL, 4194304LL);
    // fused conv + online-softmax + PV (v2: 2 k-groups, prefetch)
    conv_attn<<<dim3(256), dim3(1024), 0, stream>>>(
        SC, Vt + bQK, cw, At + bQK);
  }

  // output projection -> f32 d_out
  gemm_nt<128, 128, false, true, true><<<dim3(8, 32, 1), blk, 0, stream>>>(
      At, Wob, bo, d_out, 1024, 1024, 1024, 1024, 1.f, 0, 0, 0);
}